// Round 1
// baseline (467.172 us; speedup 1.0000x reference)
//
#include <hip/hip_runtime.h>
#include <math.h>

#define Bsz 2
#define NHd 8
#define HD 32
#define CC 256
#define Himg 56
#define Wimg 56
#define SIMG 3136
#define NQtok 15
#define SS 3151           // SIMG + NQtok
#define SP 3200           // padded to 50*64
#define NWIN 50           // 49 image windows + 1 cls block
#define WN 49
#define MM 50             // mask dim

#define QSZ (Bsz*NHd*SP*HD)     // 1,638,400 floats per tensor
#define VSPSZ (Bsz*SIMG*CC)     // 1,605,632
#define USZ (Bsz*SS*CC)         // 1,613,312

// ---------------------------------------------------------------- mask prep
// Canonicalize mask (bool bytes / int32 / float32 -> uint8), detected on device.
__global__ void prep_mask(const unsigned char* __restrict__ raw,
                          unsigned char* __restrict__ mask8) {
    __shared__ int type_s; // 0=bool bytes, 1=int32, 2=float32
    if (threadIdx.x == 0) {
        // mask[0][49][*] is all-True. In bool layout bytes 2450..2499 are 1,
        // including offsets !=0 mod 4. In 4-byte layouts those bytes are 0.
        int isbool = (raw[2453] | raw[2457] | raw[2461]) != 0;
        if (isbool) type_s = 0;
        else {
            // element 2450 (= mask[0][49][0], True) at byte 9800 in 4B layout
            unsigned int w = *(const unsigned int*)(raw + 9800);
            type_s = (w == 0x3F800000u) ? 2 : 1;
        }
    }
    __syncthreads();
    int t = type_s;
    for (int i = threadIdx.x; i < Bsz * MM * MM; i += blockDim.x) {
        unsigned char v;
        if (t == 0) v = raw[i] ? 1 : 0;
        else {
            unsigned int w = *(const unsigned int*)(raw + 4 * i);
            v = w ? 1 : 0;
        }
        mask8[i] = v;
    }
}

// ---------------------------------------------------------------- QKV GEMM
// rows = B*SP (pad tokens -> zero input), cols = 768. Scatter to window order.
__global__ __launch_bounds__(256) void qkv_gemm(
        const float* __restrict__ x, const float* __restrict__ cls,
        const float* __restrict__ Wqkv, const float* __restrict__ bqkv,
        float* __restrict__ Q, float* __restrict__ K, float* __restrict__ V,
        float* __restrict__ Vsp) {
    __shared__ __align__(16) float As[16][68];
    __shared__ __align__(16) float Bs[16][64];
    int tid = threadIdx.x;
    int tx = tid & 15, ty = tid >> 4;
    int row0 = blockIdx.x * 64;
    int col0 = blockIdx.y * 64;
    float acc[4][4] = {};
    for (int k0 = 0; k0 < 256; k0 += 16) {
        #pragma unroll
        for (int i = 0; i < 4; i++) {
            int e = tid + i * 256;
            int r = e >> 4, k = e & 15;
            int row = row0 + r;
            int b = row / SP, tok = row % SP;
            float val = 0.f;
            if (tok < SIMG)      val = x[(long)(b * SIMG + tok) * CC + k0 + k];
            else if (tok < SS)   val = cls[(long)(b * NQtok + tok - SIMG) * CC + k0 + k];
            As[k][r] = val;
        }
        #pragma unroll
        for (int i = 0; i < 4; i++) {
            int e = tid + i * 256;
            int k = e >> 6, n = e & 63;
            Bs[k][n] = Wqkv[(long)(k0 + k) * 768 + col0 + n];
        }
        __syncthreads();
        #pragma unroll
        for (int kk = 0; kk < 16; kk++) {
            float4 a4 = *(const float4*)&As[kk][ty * 4];
            float4 b4 = *(const float4*)&Bs[kk][tx * 4];
            float a[4] = {a4.x, a4.y, a4.z, a4.w};
            float bb[4] = {b4.x, b4.y, b4.z, b4.w};
            #pragma unroll
            for (int i = 0; i < 4; i++)
                #pragma unroll
                for (int j = 0; j < 4; j++)
                    acc[i][j] += a[i] * bb[j];
        }
        __syncthreads();
    }
    #pragma unroll
    for (int i = 0; i < 4; i++) {
        int row = row0 + ty * 4 + i;
        int b = row / SP, tok = row % SP;
        int s;
        if (tok < SIMG) {
            int h = tok / Wimg, w = tok % Wimg;
            s = (((h >> 3) * 7 + (w >> 3)) << 6) | ((h & 7) << 3) | (w & 7);
        } else s = tok;
        #pragma unroll
        for (int j = 0; j < 4; j++) {
            int n = col0 + tx * 4 + j;
            float v = acc[i][j] + bqkv[n];
            int which = n >> 8;
            int cch = n & 255;
            int head = cch >> 5, d = cch & 31;
            long off = (((long)(b * NHd + head)) * SP + s) * HD + d;
            if (which == 0)      Q[off] = v * 0.0625f;  // scale = 256^-0.5
            else if (which == 1) K[off] = v;
            else {
                V[off] = v;
                if (tok < SIMG) Vsp[(long)(b * SIMG + tok) * CC + cch] = v;
            }
        }
    }
}

// ---------------------------------------------------------------- attention
// One block per (b, head, q-window). Block-sparse flash over allowed k-windows.
__global__ __launch_bounds__(256) void attn_kernel(
        const float* __restrict__ Q, const float* __restrict__ K,
        const float* __restrict__ V, const unsigned char* __restrict__ mask8,
        float* __restrict__ O) {
    __shared__ __align__(16) float Ks[64][36];
    __shared__ __align__(16) float Vs[64][36];
    __shared__ float Ps[64][65];
    __shared__ float Pm[4][64];
    __shared__ float Psum[4][64];
    __shared__ float m_run[64], l_run[64];

    int blk = blockIdx.x;
    int qb = blk % NWIN;
    int bh = blk / NWIN;          // b*NH + head
    int tid = threadIdx.x;
    int r = tid & 63;
    int g = tid >> 6;

    const float* Qbase = Q + ((long)bh * SP + qb * 64) * HD;
    float qreg[32];
    {
        const float4* qrow = (const float4*)(Qbase + r * HD);
        #pragma unroll
        for (int k4 = 0; k4 < 8; k4++) {
            float4 t = qrow[k4];
            qreg[k4 * 4 + 0] = t.x; qreg[k4 * 4 + 1] = t.y;
            qreg[k4 * 4 + 2] = t.z; qreg[k4 * 4 + 3] = t.w;
        }
    }

    float acc[8] = {};
    if (tid < 64) { m_run[tid] = -INFINITY; l_run[tid] = 0.f; }
    __syncthreads();

    const unsigned char* mrow = mask8 + ((long)(bh / NHd) * MM + qb) * MM;

    for (int kb = 0; kb < NWIN; kb++) {
        if (!mrow[kb]) continue;
        const float* Kb = K + ((long)bh * SP + kb * 64) * HD;
        const float* Vb = V + ((long)bh * SP + kb * 64) * HD;
        #pragma unroll
        for (int i = 0; i < 8; i++) {
            int e = tid + i * 256;
            int rr = e >> 5, d = e & 31;
            Ks[rr][d] = Kb[e];
            Vs[rr][d] = Vb[e];
        }
        __syncthreads();

        int nk = (kb == WN) ? NQtok : 64;
        float pmax = -INFINITY;
        float pj[16];
        #pragma unroll
        for (int jj = 0; jj < 16; jj++) {
            int j = g * 16 + jj;
            const float4* krow = (const float4*)&Ks[j][0];
            float dot = 0.f;
            #pragma unroll
            for (int k4 = 0; k4 < 8; k4++) {
                float4 kv = krow[k4];
                dot += qreg[k4 * 4 + 0] * kv.x + qreg[k4 * 4 + 1] * kv.y
                     + qreg[k4 * 4 + 2] * kv.z + qreg[k4 * 4 + 3] * kv.w;
            }
            float lg = (j < nk) ? dot : -INFINITY;
            pj[jj] = lg;
            pmax = fmaxf(pmax, lg);
        }
        Pm[g][r] = pmax;
        __syncthreads();

        float m_old = m_run[r];
        float m_new = fmaxf(fmaxf(fmaxf(Pm[0][r], Pm[1][r]),
                                  fmaxf(Pm[2][r], Pm[3][r])), m_old);
        float alpha = expf(m_old - m_new);   // exp(-inf)=0 on first block
        float psum = 0.f;
        #pragma unroll
        for (int jj = 0; jj < 16; jj++) {
            float p = expf(pj[jj] - m_new);  // masked: exp(-inf)=0
            Ps[r][g * 16 + jj] = p;
            psum += p;
        }
        Psum[g][r] = psum;
        #pragma unroll
        for (int d = 0; d < 8; d++) acc[d] *= alpha;
        __syncthreads();

        #pragma unroll 8
        for (int j = 0; j < 64; j++) {
            float p = Ps[r][j];
            const float4* vrow = (const float4*)&Vs[j][g * 8];
            float4 v0 = vrow[0], v1 = vrow[1];
            acc[0] += p * v0.x; acc[1] += p * v0.y;
            acc[2] += p * v0.z; acc[3] += p * v0.w;
            acc[4] += p * v1.x; acc[5] += p * v1.y;
            acc[6] += p * v1.z; acc[7] += p * v1.w;
        }
        if (g == 0) {
            float ssum = Psum[0][r] + Psum[1][r] + Psum[2][r] + Psum[3][r];
            l_run[r] = l_run[r] * alpha + ssum;
            m_run[r] = m_new;
        }
        __syncthreads();
    }

    float inv = 1.f / l_run[r];
    float* Ob = O + ((long)bh * SP + qb * 64 + r) * HD + g * 8;
    #pragma unroll
    for (int d = 0; d < 8; d++) Ob[d] = acc[d] * inv;
}

// ---------------------------------------------------------------- gather + LEPE
// U[b][tok][c] = attn_out(un-windowed) + depthwise3x3(Vsp) for image tokens.
__global__ __launch_bounds__(256) void assemble_u(
        const float* __restrict__ O, const float* __restrict__ Vsp,
        const float* __restrict__ lepe_w, const float* __restrict__ lepe_b,
        float* __restrict__ U) {
    int row = blockIdx.x;            // b*SS + tok
    int b = row / SS, tok = row % SS;
    int c = threadIdx.x;
    int head = c >> 5, d = c & 31;
    int s;
    float lepe = 0.f;
    if (tok < SIMG) {
        int h = tok / Wimg, w = tok % Wimg;
        s = (((h >> 3) * 7 + (w >> 3)) << 6) | ((h & 7) << 3) | (w & 7);
        float acc = lepe_b[c];
        #pragma unroll
        for (int dh = -1; dh <= 1; dh++) {
            int hh = h + dh;
            if (hh < 0 || hh >= Himg) continue;
            #pragma unroll
            for (int dw = -1; dw <= 1; dw++) {
                int ww = w + dw;
                if (ww < 0 || ww >= Wimg) continue;
                acc += Vsp[((long)(b * SIMG) + hh * Wimg + ww) * CC + c]
                     * lepe_w[((dh + 1) * 3 + (dw + 1)) * CC + c];
            }
        }
        lepe = acc;
    } else {
        s = tok;                     // cls tokens sit at 3136+q
    }
    float o = O[(((long)(b * NHd + head)) * SP + s) * HD + d];
    U[(long)row * CC + c] = o + lepe;
}

// ---------------------------------------------------------------- out GEMM
__global__ __launch_bounds__(256) void out_gemm(
        const float* __restrict__ U, const float* __restrict__ Wo,
        const float* __restrict__ bo, float* __restrict__ out) {
    __shared__ __align__(16) float As[16][68];
    __shared__ __align__(16) float Bs[16][64];
    int tid = threadIdx.x;
    int tx = tid & 15, ty = tid >> 4;
    int row0 = blockIdx.x * 64;
    int col0 = blockIdx.y * 64;
    const int nrows = Bsz * SS;      // 6302
    float acc[4][4] = {};
    for (int k0 = 0; k0 < 256; k0 += 16) {
        #pragma unroll
        for (int i = 0; i < 4; i++) {
            int e = tid + i * 256;
            int r = e >> 4, k = e & 15;
            int row = row0 + r;
            As[k][r] = (row < nrows) ? U[(long)row * CC + k0 + k] : 0.f;
        }
        #pragma unroll
        for (int i = 0; i < 4; i++) {
            int e = tid + i * 256;
            int k = e >> 6, n = e & 63;
            Bs[k][n] = Wo[(long)(k0 + k) * CC + col0 + n];
        }
        __syncthreads();
        #pragma unroll
        for (int kk = 0; kk < 16; kk++) {
            float4 a4 = *(const float4*)&As[kk][ty * 4];
            float4 b4 = *(const float4*)&Bs[kk][tx * 4];
            float a[4] = {a4.x, a4.y, a4.z, a4.w};
            float bb[4] = {b4.x, b4.y, b4.z, b4.w};
            #pragma unroll
            for (int i = 0; i < 4; i++)
                #pragma unroll
                for (int j = 0; j < 4; j++)
                    acc[i][j] += a[i] * bb[j];
        }
        __syncthreads();
    }
    #pragma unroll
    for (int i = 0; i < 4; i++) {
        int row = row0 + ty * 4 + i;
        if (row >= nrows) continue;
        int b = row / SS, tok = row % SS;
        long base;
        if (tok < SIMG) base = (long)(b * SIMG + tok) * CC;
        else base = (long)Bsz * SIMG * CC + (long)(b * NQtok + tok - SIMG) * CC;
        #pragma unroll
        for (int j = 0; j < 4; j++) {
            int n = col0 + tx * 4 + j;
            out[base + n] = acc[i][j] + bo[n];
        }
    }
}

// ---------------------------------------------------------------- launch
extern "C" void kernel_launch(void* const* d_in, const int* in_sizes, int n_in,
                              void* d_out, int out_size, void* d_ws, size_t ws_size,
                              hipStream_t stream) {
    const float* x      = (const float*)d_in[0];
    const float* cls    = (const float*)d_in[1];
    const unsigned char* mask_raw = (const unsigned char*)d_in[2];
    const float* Wqkv   = (const float*)d_in[3];
    const float* bqkv   = (const float*)d_in[4];
    const float* lepe_w = (const float*)d_in[5];
    const float* lepe_b = (const float*)d_in[6];
    const float* Wo     = (const float*)d_in[7];
    const float* bo     = (const float*)d_in[8];
    float* out = (float*)d_out;

    float* Q   = (float*)d_ws;
    float* K   = Q + QSZ;
    float* V   = K + QSZ;
    float* O   = V + QSZ;
    float* Vsp = O + QSZ;
    float* U   = Vsp + VSPSZ;
    unsigned char* mask8 = (unsigned char*)(U + USZ);

    prep_mask<<<1, 256, 0, stream>>>(mask_raw, mask8);
    qkv_gemm<<<dim3(Bsz * SP / 64, 12), 256, 0, stream>>>(x, cls, Wqkv, bqkv, Q, K, V, Vsp);
    attn_kernel<<<Bsz * NHd * NWIN, 256, 0, stream>>>(Q, K, V, mask8, O);
    assemble_u<<<Bsz * SS, 256, 0, stream>>>(O, Vsp, lepe_w, lepe_b, U);
    out_gemm<<<dim3((Bsz * SS + 63) / 64, 4), 256, 0, stream>>>(U, Wo, bo, out);
}

// Round 2
// 210.340 us; speedup vs baseline: 2.2210x; 2.2210x over previous
//
#include <hip/hip_runtime.h>
#include <hip/hip_bf16.h>
#include <math.h>

#define Bsz 2
#define NHd 8
#define HD 32
#define CC 256
#define Himg 56
#define Wimg 56
#define SIMG 3136
#define NQtok 15
#define SS 3151           // SIMG + NQtok
#define SP 3200           // padded to 50*64
#define NWIN 50           // 49 image windows + 1 cls block
#define WN 49
#define MM 50             // mask dim

#define QSZ (Bsz*NHd*SP*HD)     // 1,638,400 floats per tensor
#define VSPSZ (Bsz*SIMG*CC)     // 1,605,632
#define USZ (Bsz*SS*CC)         // 1,613,312

typedef __attribute__((ext_vector_type(8))) short bf16x8;
typedef __attribute__((ext_vector_type(4))) float f32x4;

__device__ __forceinline__ short f2bf(float f) {
    __hip_bfloat16 h = __float2bfloat16(f);
    return *reinterpret_cast<short*>(&h);
}

// ---------------------------------------------------------------- mask prep
// Canonicalize mask (bool bytes / int32 / float32 -> uint8), detected on device.
__global__ void prep_mask(const unsigned char* __restrict__ raw,
                          unsigned char* __restrict__ mask8) {
    __shared__ int type_s; // 0=bool bytes, 1=int32, 2=float32
    if (threadIdx.x == 0) {
        int isbool = (raw[2453] | raw[2457] | raw[2461]) != 0;
        if (isbool) type_s = 0;
        else {
            unsigned int w = *(const unsigned int*)(raw + 9800);
            type_s = (w == 0x3F800000u) ? 2 : 1;
        }
    }
    __syncthreads();
    int t = type_s;
    for (int i = threadIdx.x; i < Bsz * MM * MM; i += blockDim.x) {
        unsigned char v;
        if (t == 0) v = raw[i] ? 1 : 0;
        else {
            unsigned int w = *(const unsigned int*)(raw + 4 * i);
            v = w ? 1 : 0;
        }
        mask8[i] = v;
    }
}

// ---------------------------------------------------------------- QKV GEMM
__global__ __launch_bounds__(256) void qkv_gemm(
        const float* __restrict__ x, const float* __restrict__ cls,
        const float* __restrict__ Wqkv, const float* __restrict__ bqkv,
        float* __restrict__ Q, float* __restrict__ K, float* __restrict__ V,
        float* __restrict__ Vsp) {
    __shared__ __align__(16) float As[16][68];
    __shared__ __align__(16) float Bs[16][64];
    int tid = threadIdx.x;
    int tx = tid & 15, ty = tid >> 4;
    int row0 = blockIdx.x * 64;
    int col0 = blockIdx.y * 64;
    float acc[4][4] = {};
    for (int k0 = 0; k0 < 256; k0 += 16) {
        #pragma unroll
        for (int i = 0; i < 4; i++) {
            int e = tid + i * 256;
            int r = e >> 4, k = e & 15;
            int row = row0 + r;
            int b = row / SP, tok = row % SP;
            float val = 0.f;
            if (tok < SIMG)      val = x[(long)(b * SIMG + tok) * CC + k0 + k];
            else if (tok < SS)   val = cls[(long)(b * NQtok + tok - SIMG) * CC + k0 + k];
            As[k][r] = val;
        }
        #pragma unroll
        for (int i = 0; i < 4; i++) {
            int e = tid + i * 256;
            int k = e >> 6, n = e & 63;
            Bs[k][n] = Wqkv[(long)(k0 + k) * 768 + col0 + n];
        }
        __syncthreads();
        #pragma unroll
        for (int kk = 0; kk < 16; kk++) {
            float4 a4 = *(const float4*)&As[kk][ty * 4];
            float4 b4 = *(const float4*)&Bs[kk][tx * 4];
            float a[4] = {a4.x, a4.y, a4.z, a4.w};
            float bb[4] = {b4.x, b4.y, b4.z, b4.w};
            #pragma unroll
            for (int i = 0; i < 4; i++)
                #pragma unroll
                for (int j = 0; j < 4; j++)
                    acc[i][j] += a[i] * bb[j];
        }
        __syncthreads();
    }
    #pragma unroll
    for (int i = 0; i < 4; i++) {
        int row = row0 + ty * 4 + i;
        int b = row / SP, tok = row % SP;
        int s;
        if (tok < SIMG) {
            int h = tok / Wimg, w = tok % Wimg;
            s = (((h >> 3) * 7 + (w >> 3)) << 6) | ((h & 7) << 3) | (w & 7);
        } else s = tok;
        #pragma unroll
        for (int j = 0; j < 4; j++) {
            int n = col0 + tx * 4 + j;
            float v = acc[i][j] + bqkv[n];
            int which = n >> 8;
            int cch = n & 255;
            int head = cch >> 5, d = cch & 31;
            long off = (((long)(b * NHd + head)) * SP + s) * HD + d;
            if (which == 0)      Q[off] = v * 0.0625f;  // scale = 256^-0.5
            else if (which == 1) K[off] = v;
            else {
                V[off] = v;
                if (tok < SIMG) Vsp[(long)(b * SIMG + tok) * CC + cch] = v;
            }
        }
    }
}

// ---------------------------------------------------------------- attention (MFMA)
// One block per (b, head, q-window); wave w owns q-rows [w*16, w*16+16).
// QK^T and PV via mfma_f32_16x16x32_bf16; softmax in registers.
__global__ __launch_bounds__(256) void attn_mfma(
        const float* __restrict__ Q, const float* __restrict__ K,
        const float* __restrict__ V, const unsigned char* __restrict__ mask8,
        float* __restrict__ O) {
    __shared__ __align__(16) short Ks[64][40];    // K window, bf16, padded (2-way max)
    __shared__ __align__(16) short Vt[32][72];    // V^T window, bf16, padded
    __shared__ __align__(16) short Pl[4][16][72]; // per-wave P strip, bf16

    int blk = blockIdx.x;
    int qb = blk % NWIN;
    int bh = blk / NWIN;          // b*NH + head
    int tid = threadIdx.x;
    int w = tid >> 6;             // wave id
    int l = tid & 63;
    int l15 = l & 15;
    int hi = l >> 4;

    // Q fragment (A operand): row = l15 (of this wave's 16-row strip), k = hi*8..+8
    const float* qp = Q + ((long)bh * SP + qb * 64 + w * 16 + l15) * HD + hi * 8;
    float4 q0 = *(const float4*)qp;
    float4 q1 = *(const float4*)(qp + 4);
    bf16x8 qf;
    qf[0] = f2bf(q0.x); qf[1] = f2bf(q0.y); qf[2] = f2bf(q0.z); qf[3] = f2bf(q0.w);
    qf[4] = f2bf(q1.x); qf[5] = f2bf(q1.y); qf[6] = f2bf(q1.z); qf[7] = f2bf(q1.w);

    f32x4 acc0 = {0.f, 0.f, 0.f, 0.f};
    f32x4 acc1 = {0.f, 0.f, 0.f, 0.f};
    float m_run[4], l_run[4];
    #pragma unroll
    for (int r = 0; r < 4; r++) { m_run[r] = -1e30f; l_run[r] = 0.f; }

    const unsigned char* mrow = mask8 + ((long)(bh / NHd) * MM + qb) * MM;
    int stok = tid >> 2;            // staging token 0..63
    int sd0 = (tid & 3) * 8;        // staging d offset {0,8,16,24}

    for (int kb = 0; kb < NWIN; kb++) {
        if (!mrow[kb]) continue;
        const float* Kb = K + ((long)bh * SP + kb * 64) * HD;
        const float* Vb = V + ((long)bh * SP + kb * 64) * HD;
        __syncthreads();     // previous iteration's reads done before overwrite
        {
            float4 a = *(const float4*)(Kb + stok * HD + sd0);
            float4 b = *(const float4*)(Kb + stok * HD + sd0 + 4);
            bf16x8 kf;
            kf[0] = f2bf(a.x); kf[1] = f2bf(a.y); kf[2] = f2bf(a.z); kf[3] = f2bf(a.w);
            kf[4] = f2bf(b.x); kf[5] = f2bf(b.y); kf[6] = f2bf(b.z); kf[7] = f2bf(b.w);
            *(bf16x8*)&Ks[stok][sd0] = kf;
            float4 c = *(const float4*)(Vb + stok * HD + sd0);
            float4 d = *(const float4*)(Vb + stok * HD + sd0 + 4);
            float vv[8] = {c.x, c.y, c.z, c.w, d.x, d.y, d.z, d.w};
            #pragma unroll
            for (int j = 0; j < 8; j++) Vt[sd0 + j][stok] = f2bf(vv[j]);
        }
        __syncthreads();

        int nk = (kb == WN) ? NQtok : 64;
        // QK^T: 4 n-tiles of 16 k-tokens each; B-frag = K^T
        f32x4 s[4];
        #pragma unroll
        for (int t = 0; t < 4; t++) {
            bf16x8 kfr = *(const bf16x8*)&Ks[t * 16 + l15][hi * 8];
            f32x4 z = {0.f, 0.f, 0.f, 0.f};
            s[t] = __builtin_amdgcn_mfma_f32_16x16x32_bf16(qf, kfr, z, 0, 0, 0);
        }
        if (nk < 64) {
            #pragma unroll
            for (int t = 0; t < 4; t++) {
                int col = t * 16 + l15;
                if (col >= nk) { s[t][0] = s[t][1] = s[t][2] = s[t][3] = -1e30f; }
            }
        }
        // online softmax per row (row = hi*4 + r; 64 cols spread over 16-lane group)
        #pragma unroll
        for (int r = 0; r < 4; r++) {
            float pm = fmaxf(fmaxf(s[0][r], s[1][r]), fmaxf(s[2][r], s[3][r]));
            pm = fmaxf(pm, __shfl_xor(pm, 1));
            pm = fmaxf(pm, __shfl_xor(pm, 2));
            pm = fmaxf(pm, __shfl_xor(pm, 4));
            pm = fmaxf(pm, __shfl_xor(pm, 8));
            float mn = fmaxf(m_run[r], pm);
            float alpha = __expf(m_run[r] - mn);
            float ps = 0.f;
            #pragma unroll
            for (int t = 0; t < 4; t++) {
                float p = __expf(s[t][r] - mn);
                s[t][r] = p;
                ps += p;
            }
            ps += __shfl_xor(ps, 1);
            ps += __shfl_xor(ps, 2);
            ps += __shfl_xor(ps, 4);
            ps += __shfl_xor(ps, 8);
            l_run[r] = l_run[r] * alpha + ps;
            m_run[r] = mn;
            acc0[r] *= alpha;
            acc1[r] *= alpha;
            #pragma unroll
            for (int t = 0; t < 4; t++)
                Pl[w][hi * 4 + r][t * 16 + l15] = f2bf(s[t][r]);
        }
        // PV: O(16x32) += P(16x64) * V(64x32); A from Pl, B from Vt
        #pragma unroll
        for (int c = 0; c < 2; c++) {
            bf16x8 pa = *(const bf16x8*)&Pl[w][l15][c * 32 + hi * 8];
            bf16x8 v0 = *(const bf16x8*)&Vt[l15][c * 32 + hi * 8];
            bf16x8 v1 = *(const bf16x8*)&Vt[16 + l15][c * 32 + hi * 8];
            acc0 = __builtin_amdgcn_mfma_f32_16x16x32_bf16(pa, v0, acc0, 0, 0, 0);
            acc1 = __builtin_amdgcn_mfma_f32_16x16x32_bf16(pa, v1, acc1, 0, 0, 0);
        }
    }

    float* Ob = O + ((long)bh * SP + qb * 64 + w * 16) * HD;
    #pragma unroll
    for (int r = 0; r < 4; r++) {
        float inv = 1.f / l_run[r];
        Ob[(hi * 4 + r) * HD + l15]      = acc0[r] * inv;
        Ob[(hi * 4 + r) * HD + 16 + l15] = acc1[r] * inv;
    }
}

// ---------------------------------------------------------------- gather + LEPE
__global__ __launch_bounds__(256) void assemble_u(
        const float* __restrict__ O, const float* __restrict__ Vsp,
        const float* __restrict__ lepe_w, const float* __restrict__ lepe_b,
        float* __restrict__ U) {
    int row = blockIdx.x;            // b*SS + tok
    int b = row / SS, tok = row % SS;
    int c = threadIdx.x;
    int head = c >> 5, d = c & 31;
    int s;
    float lepe = 0.f;
    if (tok < SIMG) {
        int h = tok / Wimg, w = tok % Wimg;
        s = (((h >> 3) * 7 + (w >> 3)) << 6) | ((h & 7) << 3) | (w & 7);
        float acc = lepe_b[c];
        #pragma unroll
        for (int dh = -1; dh <= 1; dh++) {
            int hh = h + dh;
            if (hh < 0 || hh >= Himg) continue;
            #pragma unroll
            for (int dw = -1; dw <= 1; dw++) {
                int ww = w + dw;
                if (ww < 0 || ww >= Wimg) continue;
                acc += Vsp[((long)(b * SIMG) + hh * Wimg + ww) * CC + c]
                     * lepe_w[((dh + 1) * 3 + (dw + 1)) * CC + c];
            }
        }
        lepe = acc;
    } else {
        s = tok;
    }
    float o = O[(((long)(b * NHd + head)) * SP + s) * HD + d];
    U[(long)row * CC + c] = o + lepe;
}

// ---------------------------------------------------------------- out GEMM
__global__ __launch_bounds__(256) void out_gemm(
        const float* __restrict__ U, const float* __restrict__ Wo,
        const float* __restrict__ bo, float* __restrict__ out) {
    __shared__ __align__(16) float As[16][68];
    __shared__ __align__(16) float Bs[16][64];
    int tid = threadIdx.x;
    int tx = tid & 15, ty = tid >> 4;
    int row0 = blockIdx.x * 64;
    int col0 = blockIdx.y * 64;
    const int nrows = Bsz * SS;      // 6302
    float acc[4][4] = {};
    for (int k0 = 0; k0 < 256; k0 += 16) {
        #pragma unroll
        for (int i = 0; i < 4; i++) {
            int e = tid + i * 256;
            int r = e >> 4, k = e & 15;
            int row = row0 + r;
            As[k][r] = (row < nrows) ? U[(long)row * CC + k0 + k] : 0.f;
        }
        #pragma unroll
        for (int i = 0; i < 4; i++) {
            int e = tid + i * 256;
            int k = e >> 6, n = e & 63;
            Bs[k][n] = Wo[(long)(k0 + k) * CC + col0 + n];
        }
        __syncthreads();
        #pragma unroll
        for (int kk = 0; kk < 16; kk++) {
            float4 a4 = *(const float4*)&As[kk][ty * 4];
            float4 b4 = *(const float4*)&Bs[kk][tx * 4];
            float a[4] = {a4.x, a4.y, a4.z, a4.w};
            float bb[4] = {b4.x, b4.y, b4.z, b4.w};
            #pragma unroll
            for (int i = 0; i < 4; i++)
                #pragma unroll
                for (int j = 0; j < 4; j++)
                    acc[i][j] += a[i] * bb[j];
        }
        __syncthreads();
    }
    #pragma unroll
    for (int i = 0; i < 4; i++) {
        int row = row0 + ty * 4 + i;
        if (row >= nrows) continue;
        int b = row / SS, tok = row % SS;
        long base;
        if (tok < SIMG) base = (long)(b * SIMG + tok) * CC;
        else base = (long)Bsz * SIMG * CC + (long)(b * NQtok + tok - SIMG) * CC;
        #pragma unroll
        for (int j = 0; j < 4; j++) {
            int n = col0 + tx * 4 + j;
            out[base + n] = acc[i][j] + bo[n];
        }
    }
}

// ---------------------------------------------------------------- launch
extern "C" void kernel_launch(void* const* d_in, const int* in_sizes, int n_in,
                              void* d_out, int out_size, void* d_ws, size_t ws_size,
                              hipStream_t stream) {
    const float* x      = (const float*)d_in[0];
    const float* cls    = (const float*)d_in[1];
    const unsigned char* mask_raw = (const unsigned char*)d_in[2];
    const float* Wqkv   = (const float*)d_in[3];
    const float* bqkv   = (const float*)d_in[4];
    const float* lepe_w = (const float*)d_in[5];
    const float* lepe_b = (const float*)d_in[6];
    const float* Wo     = (const float*)d_in[7];
    const float* bo     = (const float*)d_in[8];
    float* out = (float*)d_out;

    float* Q   = (float*)d_ws;
    float* K   = Q + QSZ;
    float* V   = K + QSZ;
    float* O   = V + QSZ;
    float* Vsp = O + QSZ;
    float* U   = Vsp + VSPSZ;
    unsigned char* mask8 = (unsigned char*)(U + USZ);

    prep_mask<<<1, 256, 0, stream>>>(mask_raw, mask8);
    qkv_gemm<<<dim3(Bsz * SP / 64, 12), 256, 0, stream>>>(x, cls, Wqkv, bqkv, Q, K, V, Vsp);
    attn_mfma<<<Bsz * NHd * NWIN, 256, 0, stream>>>(Q, K, V, mask8, O);
    assemble_u<<<Bsz * SS, 256, 0, stream>>>(O, Vsp, lepe_w, lepe_b, U);
    out_gemm<<<dim3((Bsz * SS + 63) / 64, 4), 256, 0, stream>>>(U, Wo, bo, out);
}

// Round 3
// 141.924 us; speedup vs baseline: 3.2917x; 1.4821x over previous
//
#include <hip/hip_runtime.h>
#include <hip/hip_bf16.h>
#include <math.h>

#define Bsz 2
#define NHd 8
#define HD 32
#define CC 256
#define Himg 56
#define Wimg 56
#define SIMG 3136
#define NQtok 15
#define SS 3151           // SIMG + NQtok
#define SP 3200           // padded to 50*64
#define NWIN 50           // 49 image windows + 1 cls block
#define WN 49
#define MM 50             // mask dim

#define QSZ (Bsz*NHd*SP*HD)     // 1,638,400 elements per tensor
#define VSPSZ (Bsz*SIMG*CC)     // 1,605,632
#define USZ (Bsz*SS*CC)         // 1,613,312

typedef __attribute__((ext_vector_type(8))) short bf16x8;
typedef __attribute__((ext_vector_type(4))) float f32x4;

__device__ __forceinline__ short f2bf(float f) {
    __hip_bfloat16 h = __float2bfloat16(f);
    return *reinterpret_cast<short*>(&h);
}

// ---------------------------------------------------------------- mask prep
__global__ void prep_mask(const unsigned char* __restrict__ raw,
                          unsigned char* __restrict__ mask8) {
    __shared__ int type_s; // 0=bool bytes, 1=int32, 2=float32
    if (threadIdx.x == 0) {
        int isbool = (raw[2453] | raw[2457] | raw[2461]) != 0;
        if (isbool) type_s = 0;
        else {
            unsigned int w = *(const unsigned int*)(raw + 9800);
            type_s = (w == 0x3F800000u) ? 2 : 1;
        }
    }
    __syncthreads();
    int t = type_s;
    for (int i = threadIdx.x; i < Bsz * MM * MM; i += blockDim.x) {
        unsigned char v;
        if (t == 0) v = raw[i] ? 1 : 0;
        else {
            unsigned int w = *(const unsigned int*)(raw + 4 * i);
            v = w ? 1 : 0;
        }
        mask8[i] = v;
    }
}

// ---------------------------------------------------------------- QKV GEMM
// Emits bf16 Qbf (scaled), Kbf (window-row-major), Vtb (window [d][tok]),
// plus f32 Vsp (spatial V for LEPE).
__global__ __launch_bounds__(256) void qkv_gemm(
        const float* __restrict__ x, const float* __restrict__ cls,
        const float* __restrict__ Wqkv, const float* __restrict__ bqkv,
        short* __restrict__ Qbf, short* __restrict__ Kbf, short* __restrict__ Vtb,
        float* __restrict__ Vsp) {
    __shared__ __align__(16) float As[16][68];
    __shared__ __align__(16) float Bs[16][64];
    int tid = threadIdx.x;
    int tx = tid & 15, ty = tid >> 4;
    int row0 = blockIdx.x * 64;
    int col0 = blockIdx.y * 64;
    float acc[4][4] = {};
    for (int k0 = 0; k0 < 256; k0 += 16) {
        #pragma unroll
        for (int i = 0; i < 4; i++) {
            int e = tid + i * 256;
            int r = e >> 4, k = e & 15;
            int row = row0 + r;
            int b = row / SP, tok = row % SP;
            float val = 0.f;
            if (tok < SIMG)      val = x[(long)(b * SIMG + tok) * CC + k0 + k];
            else if (tok < SS)   val = cls[(long)(b * NQtok + tok - SIMG) * CC + k0 + k];
            As[k][r] = val;
        }
        #pragma unroll
        for (int i = 0; i < 4; i++) {
            int e = tid + i * 256;
            int k = e >> 6, n = e & 63;
            Bs[k][n] = Wqkv[(long)(k0 + k) * 768 + col0 + n];
        }
        __syncthreads();
        #pragma unroll
        for (int kk = 0; kk < 16; kk++) {
            float4 a4 = *(const float4*)&As[kk][ty * 4];
            float4 b4 = *(const float4*)&Bs[kk][tx * 4];
            float a[4] = {a4.x, a4.y, a4.z, a4.w};
            float bb[4] = {b4.x, b4.y, b4.z, b4.w};
            #pragma unroll
            for (int i = 0; i < 4; i++)
                #pragma unroll
                for (int j = 0; j < 4; j++)
                    acc[i][j] += a[i] * bb[j];
        }
        __syncthreads();
    }
    #pragma unroll
    for (int i = 0; i < 4; i++) {
        int row = row0 + ty * 4 + i;
        int b = row / SP, tok = row % SP;
        int s;
        if (tok < SIMG) {
            int h = tok / Wimg, w = tok % Wimg;
            s = (((h >> 3) * 7 + (w >> 3)) << 6) | ((h & 7) << 3) | (w & 7);
        } else s = tok;
        #pragma unroll
        for (int j = 0; j < 4; j++) {
            int n = col0 + tx * 4 + j;
            float v = acc[i][j] + bqkv[n];
            int which = n >> 8;
            int cch = n & 255;
            int head = cch >> 5, d = cch & 31;
            long off = (((long)(b * NHd + head)) * SP + s) * HD + d;
            if (which == 0)      Qbf[off] = f2bf(v * 0.0625f);  // scale = 256^-0.5
            else if (which == 1) Kbf[off] = f2bf(v);
            else {
                // Vtb: [(bh*NWIN + win)][d][tok]  (2048 elems per window)
                Vtb[(((long)(b * NHd + head)) * NWIN + (s >> 6)) * 2048
                    + d * 64 + (s & 63)] = f2bf(v);
                if (tok < SIMG) Vsp[(long)(b * SIMG + tok) * CC + cch] = v;
            }
        }
    }
}

// ---------------------------------------------------------------- attention
// One block per (b,head,qwin); 4 independent waves (no barriers in main loop).
// Image windows: wave w owns q-rows [w*16,w*16+16), iterates allowed k-windows.
// Cls window (qb==49): all waves share rows 0..15, split k-windows 4-way,
// merge (m,l,acc) via LDS at the end.
__global__ __launch_bounds__(256) void attn_mfma(
        const short* __restrict__ Qbf, const short* __restrict__ Kbf,
        const short* __restrict__ Vtb, const unsigned char* __restrict__ mask8,
        float* __restrict__ O) {
    __shared__ __align__(16) short Pl[4][16][72];
    __shared__ float Ms[4][16], Ls[4][16];
    __shared__ float MAcc[4][16][32];

    int qb = blockIdx.x % NWIN;
    int bh = blockIdx.x / NWIN;
    int tid = threadIdx.x;
    int w = tid >> 6;
    int l = tid & 63;
    int l15 = l & 15;
    int hi = l >> 4;
    bool is_cls = (qb == WN);
    int qrow0 = is_cls ? 0 : w * 16;

    bf16x8 qf = *(const bf16x8*)&Qbf[((long)bh * SP + qb * 64 + qrow0 + l15) * HD + hi * 8];

    f32x4 acc0 = {0.f, 0.f, 0.f, 0.f};
    f32x4 acc1 = {0.f, 0.f, 0.f, 0.f};
    float m_run[4], l_run[4];
    #pragma unroll
    for (int r = 0; r < 4; r++) { m_run[r] = -1e30f; l_run[r] = 0.f; }

    const unsigned char* mrow = mask8 + ((long)(bh / NHd) * MM + qb) * MM;
    int kb0 = is_cls ? w : 0;
    int kstep = is_cls ? 4 : 1;

    for (int kb = kb0; kb < NWIN; kb += kstep) {
        if (!is_cls && !mrow[kb]) continue;
        long kbase = ((long)bh * SP + kb * 64) * HD;   // == (bh*NWIN+kb)*2048

        // QK^T: 4 B-frags straight from global bf16 K
        f32x4 s[4];
        #pragma unroll
        for (int t = 0; t < 4; t++) {
            bf16x8 kfr = *(const bf16x8*)&Kbf[kbase + (t * 16 + l15) * HD + hi * 8];
            f32x4 z = {0.f, 0.f, 0.f, 0.f};
            s[t] = __builtin_amdgcn_mfma_f32_16x16x32_bf16(qf, kfr, z, 0, 0, 0);
        }
        if (kb == WN) {
            #pragma unroll
            for (int t = 0; t < 4; t++)
                if (t * 16 + l15 >= NQtok) { s[t][0] = s[t][1] = s[t][2] = s[t][3] = -1e30f; }
        }
        // online softmax, rows = hi*4+r, cols spread over 16-lane group
        #pragma unroll
        for (int r = 0; r < 4; r++) {
            float pm = fmaxf(fmaxf(s[0][r], s[1][r]), fmaxf(s[2][r], s[3][r]));
            pm = fmaxf(pm, __shfl_xor(pm, 1));
            pm = fmaxf(pm, __shfl_xor(pm, 2));
            pm = fmaxf(pm, __shfl_xor(pm, 4));
            pm = fmaxf(pm, __shfl_xor(pm, 8));
            float mn = fmaxf(m_run[r], pm);
            float alpha = __expf(m_run[r] - mn);
            float ps = 0.f;
            #pragma unroll
            for (int t = 0; t < 4; t++) {
                float p = __expf(s[t][r] - mn);
                s[t][r] = p;
                ps += p;
            }
            ps += __shfl_xor(ps, 1);
            ps += __shfl_xor(ps, 2);
            ps += __shfl_xor(ps, 4);
            ps += __shfl_xor(ps, 8);
            l_run[r] = l_run[r] * alpha + ps;
            m_run[r] = mn;
            acc0[r] *= alpha;
            acc1[r] *= alpha;
            #pragma unroll
            for (int t = 0; t < 4; t++)
                Pl[w][hi * 4 + r][t * 16 + l15] = f2bf(s[t][r]);
        }
        // PV: A-frag from per-wave LDS strip, B-frags straight from global Vtb
        #pragma unroll
        for (int c = 0; c < 2; c++) {
            bf16x8 pa = *(const bf16x8*)&Pl[w][l15][c * 32 + hi * 8];
            bf16x8 v0 = *(const bf16x8*)&Vtb[kbase + l15 * 64 + c * 32 + hi * 8];
            bf16x8 v1 = *(const bf16x8*)&Vtb[kbase + (16 + l15) * 64 + c * 32 + hi * 8];
            acc0 = __builtin_amdgcn_mfma_f32_16x16x32_bf16(pa, v0, acc0, 0, 0, 0);
            acc1 = __builtin_amdgcn_mfma_f32_16x16x32_bf16(pa, v1, acc1, 0, 0, 0);
        }
    }

    if (!is_cls) {
        float* Ob = O + ((long)bh * SP + qb * 64 + w * 16) * HD;
        #pragma unroll
        for (int r = 0; r < 4; r++) {
            float inv = 1.f / l_run[r];
            Ob[(hi * 4 + r) * HD + l15]      = acc0[r] * inv;
            Ob[(hi * 4 + r) * HD + 16 + l15] = acc1[r] * inv;
        }
    } else {
        // merge 4 partial flash states
        #pragma unroll
        for (int r = 0; r < 4; r++) {
            int row = hi * 4 + r;
            if (l15 == 0) { Ms[w][row] = m_run[r]; Ls[w][row] = l_run[r]; }
            MAcc[w][row][l15]      = acc0[r];
            MAcc[w][row][16 + l15] = acc1[r];
        }
        __syncthreads();
        if (w == 0) {
            float* Ob = O + ((long)bh * SP + WN * 64) * HD;
            #pragma unroll
            for (int r = 0; r < 4; r++) {
                int row = hi * 4 + r;
                float M = fmaxf(fmaxf(Ms[0][row], Ms[1][row]),
                                fmaxf(Ms[2][row], Ms[3][row]));
                float L = 0.f, o0 = 0.f, o1 = 0.f;
                #pragma unroll
                for (int ww = 0; ww < 4; ww++) {
                    float sc = __expf(Ms[ww][row] - M);
                    L  += Ls[ww][row] * sc;
                    o0 += MAcc[ww][row][l15] * sc;
                    o1 += MAcc[ww][row][16 + l15] * sc;
                }
                float inv = 1.f / L;
                Ob[row * HD + l15]      = o0 * inv;
                Ob[row * HD + 16 + l15] = o1 * inv;
            }
        }
    }
}

// ---------------------------------------------------------------- gather + LEPE
__global__ __launch_bounds__(256) void assemble_u(
        const float* __restrict__ O, const float* __restrict__ Vsp,
        const float* __restrict__ lepe_w, const float* __restrict__ lepe_b,
        float* __restrict__ U) {
    int row = blockIdx.x;            // b*SS + tok
    int b = row / SS, tok = row % SS;
    int c = threadIdx.x;
    int head = c >> 5, d = c & 31;
    int s;
    float lepe = 0.f;
    if (tok < SIMG) {
        int h = tok / Wimg, w = tok % Wimg;
        s = (((h >> 3) * 7 + (w >> 3)) << 6) | ((h & 7) << 3) | (w & 7);
        float acc = lepe_b[c];
        #pragma unroll
        for (int dh = -1; dh <= 1; dh++) {
            int hh = h + dh;
            if (hh < 0 || hh >= Himg) continue;
            #pragma unroll
            for (int dw = -1; dw <= 1; dw++) {
                int ww = w + dw;
                if (ww < 0 || ww >= Wimg) continue;
                acc += Vsp[((long)(b * SIMG) + hh * Wimg + ww) * CC + c]
                     * lepe_w[((dh + 1) * 3 + (dw + 1)) * CC + c];
            }
        }
        lepe = acc;
    } else {
        s = tok;
    }
    float o = O[(((long)(b * NHd + head)) * SP + s) * HD + d];
    U[(long)row * CC + c] = o + lepe;
}

// ---------------------------------------------------------------- out GEMM
__global__ __launch_bounds__(256) void out_gemm(
        const float* __restrict__ U, const float* __restrict__ Wo,
        const float* __restrict__ bo, float* __restrict__ out) {
    __shared__ __align__(16) float As[16][68];
    __shared__ __align__(16) float Bs[16][64];
    int tid = threadIdx.x;
    int tx = tid & 15, ty = tid >> 4;
    int row0 = blockIdx.x * 64;
    int col0 = blockIdx.y * 64;
    const int nrows = Bsz * SS;      // 6302
    float acc[4][4] = {};
    for (int k0 = 0; k0 < 256; k0 += 16) {
        #pragma unroll
        for (int i = 0; i < 4; i++) {
            int e = tid + i * 256;
            int r = e >> 4, k = e & 15;
            int row = row0 + r;
            As[k][r] = (row < nrows) ? U[(long)row * CC + k0 + k] : 0.f;
        }
        #pragma unroll
        for (int i = 0; i < 4; i++) {
            int e = tid + i * 256;
            int k = e >> 6, n = e & 63;
            Bs[k][n] = Wo[(long)(k0 + k) * CC + col0 + n];
        }
        __syncthreads();
        #pragma unroll
        for (int kk = 0; kk < 16; kk++) {
            float4 a4 = *(const float4*)&As[kk][ty * 4];
            float4 b4 = *(const float4*)&Bs[kk][tx * 4];
            float a[4] = {a4.x, a4.y, a4.z, a4.w};
            float bb[4] = {b4.x, b4.y, b4.z, b4.w};
            #pragma unroll
            for (int i = 0; i < 4; i++)
                #pragma unroll
                for (int j = 0; j < 4; j++)
                    acc[i][j] += a[i] * bb[j];
        }
        __syncthreads();
    }
    #pragma unroll
    for (int i = 0; i < 4; i++) {
        int row = row0 + ty * 4 + i;
        if (row >= nrows) continue;
        int b = row / SS, tok = row % SS;
        long base;
        if (tok < SIMG) base = (long)(b * SIMG + tok) * CC;
        else base = (long)Bsz * SIMG * CC + (long)(b * NQtok + tok - SIMG) * CC;
        #pragma unroll
        for (int j = 0; j < 4; j++) {
            int n = col0 + tx * 4 + j;
            out[base + n] = acc[i][j] + bo[n];
        }
    }
}

// ---------------------------------------------------------------- launch
extern "C" void kernel_launch(void* const* d_in, const int* in_sizes, int n_in,
                              void* d_out, int out_size, void* d_ws, size_t ws_size,
                              hipStream_t stream) {
    const float* x      = (const float*)d_in[0];
    const float* cls    = (const float*)d_in[1];
    const unsigned char* mask_raw = (const unsigned char*)d_in[2];
    const float* Wqkv   = (const float*)d_in[3];
    const float* bqkv   = (const float*)d_in[4];
    const float* lepe_w = (const float*)d_in[5];
    const float* lepe_b = (const float*)d_in[6];
    const float* Wo     = (const float*)d_in[7];
    const float* bo     = (const float*)d_in[8];
    float* out = (float*)d_out;

    short* Qbf = (short*)d_ws;
    short* Kbf = Qbf + QSZ;
    short* Vtb = Kbf + QSZ;
    float* O   = (float*)(Vtb + QSZ);
    float* Vsp = O + QSZ;
    float* U   = Vsp + VSPSZ;
    unsigned char* mask8 = (unsigned char*)(U + USZ);

    prep_mask<<<1, 256, 0, stream>>>(mask_raw, mask8);
    qkv_gemm<<<dim3(Bsz * SP / 64, 12), 256, 0, stream>>>(x, cls, Wqkv, bqkv, Qbf, Kbf, Vtb, Vsp);
    attn_mfma<<<Bsz * NHd * NWIN, 256, 0, stream>>>(Qbf, Kbf, Vtb, mask8, O);
    assemble_u<<<Bsz * SS, 256, 0, stream>>>(O, Vsp, lepe_w, lepe_b, U);
    out_gemm<<<dim3((Bsz * SS + 63) / 64, 4), 256, 0, stream>>>(U, Wo, bo, out);
}

// Round 4
// 107.461 us; speedup vs baseline: 4.3474x; 1.3207x over previous
//
#include <hip/hip_runtime.h>
#include <hip/hip_bf16.h>
#include <math.h>

#define Bsz 2
#define NHd 8
#define HD 32
#define CC 256
#define Himg 56
#define Wimg 56
#define SIMG 3136
#define NQtok 15
#define SS 3151           // SIMG + NQtok
#define SP 3200           // padded to 50*64
#define NWIN 50           // 49 image windows + 1 cls block
#define WN 49
#define MM 50             // mask dim
#define MROWS (Bsz*SP)    // 6400 padded token rows

#define QSZ (Bsz*NHd*SP*HD)     // 1,638,400 elements per tensor
#define VSPSZ (Bsz*SIMG*CC)     // 1,605,632
#define ASZ (MROWS*CC)          // 1,638,400
#define WTSZ (768*CC)           // 196,608
#define WOTSZ (CC*CC)           // 65,536
#define USZ2 (MROWS*CC)         // 1,638,400 (bf16 U, padded)

typedef __attribute__((ext_vector_type(8))) short bf16x8;
typedef __attribute__((ext_vector_type(4))) float f32x4;

__device__ __forceinline__ short f2bf(float f) {
    __hip_bfloat16 h = __float2bfloat16(f);
    return *reinterpret_cast<short*>(&h);
}

// ---------------------------------------------------------------- mask prep
__global__ void prep_mask(const unsigned char* __restrict__ raw,
                          unsigned char* __restrict__ mask8) {
    __shared__ int type_s; // 0=bool bytes, 1=int32, 2=float32
    if (threadIdx.x == 0) {
        int isbool = (raw[2453] | raw[2457] | raw[2461]) != 0;
        if (isbool) type_s = 0;
        else {
            unsigned int w = *(const unsigned int*)(raw + 9800);
            type_s = (w == 0x3F800000u) ? 2 : 1;
        }
    }
    __syncthreads();
    int t = type_s;
    for (int i = threadIdx.x; i < Bsz * MM * MM; i += blockDim.x) {
        unsigned char v;
        if (t == 0) v = raw[i] ? 1 : 0;
        else {
            unsigned int w = *(const unsigned int*)(raw + 4 * i);
            v = w ? 1 : 0;
        }
        mask8[i] = v;
    }
}

// ---------------------------------------------------------------- cast prep
// Abf[6400][256] = bf16(x ‖ cls ‖ 0); Wt = bf16(Wqkv^T); Wot = bf16(Wo^T)
__global__ __launch_bounds__(256) void cast_prep(
        const float* __restrict__ x, const float* __restrict__ cls,
        const float* __restrict__ Wqkv, const float* __restrict__ Wo,
        short* __restrict__ Abf, short* __restrict__ Wt, short* __restrict__ Wot) {
    int bid = blockIdx.x;
    int tid = threadIdx.x;
    if (bid < 800) {                       // Abf: 204800 chunks of 8
        int idx = bid * 256 + tid;
        int row = idx >> 5;                // 32 chunks per 256-col row
        int c8 = (idx & 31) * 8;
        int b = row / SP, tok = row % SP;
        bf16x8 o = {0, 0, 0, 0, 0, 0, 0, 0};
        const float* p = nullptr;
        if (tok < SIMG)      p = x + (long)(b * SIMG + tok) * CC + c8;
        else if (tok < SS)   p = cls + (long)(b * NQtok + tok - SIMG) * CC + c8;
        if (p) {
            float4 a = *(const float4*)p, bb = *(const float4*)(p + 4);
            o[0] = f2bf(a.x); o[1] = f2bf(a.y); o[2] = f2bf(a.z); o[3] = f2bf(a.w);
            o[4] = f2bf(bb.x); o[5] = f2bf(bb.y); o[6] = f2bf(bb.z); o[7] = f2bf(bb.w);
        }
        *(bf16x8*)(Abf + (long)row * CC + c8) = o;
    } else if (bid < 896) {                // Wt: 24576 chunks
        int idx = (bid - 800) * 256 + tid;
        int n = idx >> 5;
        int k8 = (idx & 31) * 8;
        bf16x8 o;
        #pragma unroll
        for (int j = 0; j < 8; j++) o[j] = f2bf(Wqkv[(long)(k8 + j) * 768 + n]);
        *(bf16x8*)(Wt + (long)n * CC + k8) = o;
    } else {                               // Wot: 8192 chunks
        int idx = (bid - 896) * 256 + tid;
        int n = idx >> 5;
        int k8 = (idx & 31) * 8;
        bf16x8 o;
        #pragma unroll
        for (int j = 0; j < 8; j++) o[j] = f2bf(Wo[(long)(k8 + j) * CC + n]);
        *(bf16x8*)(Wot + (long)n * CC + k8) = o;
    }
}

// ---------------------------------------------------------------- QKV GEMM (MFMA)
// C[6400][768] = Abf @ Wqkv; no LDS, fragments straight from global (L2).
// Epilogue scatters to Qbf (scaled), Kbf, Vtb (window [d][tok]), Vsp (f32).
__global__ __launch_bounds__(256) void qkv_gemm_mfma(
        const short* __restrict__ Abf, const short* __restrict__ Wt,
        const float* __restrict__ bqkv,
        short* __restrict__ Qbf, short* __restrict__ Kbf, short* __restrict__ Vtb,
        float* __restrict__ Vsp) {
    int tid = threadIdx.x;
    int w = tid >> 6, l = tid & 63, l15 = l & 15, hi = l >> 4;
    int row0 = blockIdx.x * 64 + w * 16;
    int n0 = blockIdx.y * 64;
    f32x4 acc[4];
    #pragma unroll
    for (int t = 0; t < 4; t++) acc[t] = (f32x4){0.f, 0.f, 0.f, 0.f};
    const short* Ap = Abf + (long)(row0 + l15) * CC + hi * 8;
    const short* Bp = Wt + (long)(n0 + l15) * CC + hi * 8;
    #pragma unroll
    for (int k0 = 0; k0 < 256; k0 += 32) {
        bf16x8 af = *(const bf16x8*)(Ap + k0);
        #pragma unroll
        for (int t = 0; t < 4; t++) {
            bf16x8 bf = *(const bf16x8*)(Bp + t * 16 * CC + k0);
            acc[t] = __builtin_amdgcn_mfma_f32_16x16x32_bf16(af, bf, acc[t], 0, 0, 0);
        }
    }
    int which = n0 >> 8;                  // 0=Q 1=K 2=V (uniform per block)
    #pragma unroll
    for (int r = 0; r < 4; r++) {
        int row = row0 + hi * 4 + r;
        int b = row / SP, tok = row % SP;
        int s;
        if (tok < SIMG) {
            int h = tok / Wimg, wq = tok % Wimg;
            s = (((h >> 3) * 7 + (wq >> 3)) << 6) | ((h & 7) << 3) | (wq & 7);
        } else s = tok;
        #pragma unroll
        for (int t = 0; t < 4; t++) {
            int n = n0 + t * 16 + l15;
            float v = acc[t][r] + bqkv[n];
            int cch = n & 255;
            int head = cch >> 5, d = cch & 31;
            long off = (((long)(b * NHd + head)) * SP + s) * HD + d;
            if (which == 0)      Qbf[off] = f2bf(v * 0.0625f);   // scale = 256^-0.5
            else if (which == 1) Kbf[off] = f2bf(v);
            else {
                Vtb[(((long)(b * NHd + head)) * NWIN + (s >> 6)) * 2048
                    + d * 64 + (s & 63)] = f2bf(v);
                if (tok < SIMG) Vsp[(long)(b * SIMG + tok) * CC + cch] = v;
            }
        }
    }
}

// ---------------------------------------------------------------- attention
__global__ __launch_bounds__(256) void attn_mfma(
        const short* __restrict__ Qbf, const short* __restrict__ Kbf,
        const short* __restrict__ Vtb, const unsigned char* __restrict__ mask8,
        float* __restrict__ O) {
    __shared__ __align__(16) short Pl[4][16][72];
    __shared__ float Ms[4][16], Ls[4][16];
    __shared__ float MAcc[4][16][32];

    int qb = blockIdx.x % NWIN;
    int bh = blockIdx.x / NWIN;
    int tid = threadIdx.x;
    int w = tid >> 6;
    int l = tid & 63;
    int l15 = l & 15;
    int hi = l >> 4;
    bool is_cls = (qb == WN);
    int qrow0 = is_cls ? 0 : w * 16;

    bf16x8 qf = *(const bf16x8*)&Qbf[((long)bh * SP + qb * 64 + qrow0 + l15) * HD + hi * 8];

    f32x4 acc0 = {0.f, 0.f, 0.f, 0.f};
    f32x4 acc1 = {0.f, 0.f, 0.f, 0.f};
    float m_run[4], l_run[4];
    #pragma unroll
    for (int r = 0; r < 4; r++) { m_run[r] = -1e30f; l_run[r] = 0.f; }

    const unsigned char* mrow = mask8 + ((long)(bh / NHd) * MM + qb) * MM;
    int kb0 = is_cls ? w : 0;
    int kstep = is_cls ? 4 : 1;

    for (int kb = kb0; kb < NWIN; kb += kstep) {
        if (!is_cls && !mrow[kb]) continue;
        long kbase = ((long)bh * SP + kb * 64) * HD;

        f32x4 s[4];
        #pragma unroll
        for (int t = 0; t < 4; t++) {
            bf16x8 kfr = *(const bf16x8*)&Kbf[kbase + (t * 16 + l15) * HD + hi * 8];
            f32x4 z = {0.f, 0.f, 0.f, 0.f};
            s[t] = __builtin_amdgcn_mfma_f32_16x16x32_bf16(qf, kfr, z, 0, 0, 0);
        }
        if (kb == WN) {
            #pragma unroll
            for (int t = 0; t < 4; t++)
                if (t * 16 + l15 >= NQtok) { s[t][0] = s[t][1] = s[t][2] = s[t][3] = -1e30f; }
        }
        #pragma unroll
        for (int r = 0; r < 4; r++) {
            float pm = fmaxf(fmaxf(s[0][r], s[1][r]), fmaxf(s[2][r], s[3][r]));
            pm = fmaxf(pm, __shfl_xor(pm, 1));
            pm = fmaxf(pm, __shfl_xor(pm, 2));
            pm = fmaxf(pm, __shfl_xor(pm, 4));
            pm = fmaxf(pm, __shfl_xor(pm, 8));
            float mn = fmaxf(m_run[r], pm);
            float alpha = __expf(m_run[r] - mn);
            float ps = 0.f;
            #pragma unroll
            for (int t = 0; t < 4; t++) {
                float p = __expf(s[t][r] - mn);
                s[t][r] = p;
                ps += p;
            }
            ps += __shfl_xor(ps, 1);
            ps += __shfl_xor(ps, 2);
            ps += __shfl_xor(ps, 4);
            ps += __shfl_xor(ps, 8);
            l_run[r] = l_run[r] * alpha + ps;
            m_run[r] = mn;
            acc0[r] *= alpha;
            acc1[r] *= alpha;
            #pragma unroll
            for (int t = 0; t < 4; t++)
                Pl[w][hi * 4 + r][t * 16 + l15] = f2bf(s[t][r]);
        }
        #pragma unroll
        for (int c = 0; c < 2; c++) {
            bf16x8 pa = *(const bf16x8*)&Pl[w][l15][c * 32 + hi * 8];
            bf16x8 v0 = *(const bf16x8*)&Vtb[kbase + l15 * 64 + c * 32 + hi * 8];
            bf16x8 v1 = *(const bf16x8*)&Vtb[kbase + (16 + l15) * 64 + c * 32 + hi * 8];
            acc0 = __builtin_amdgcn_mfma_f32_16x16x32_bf16(pa, v0, acc0, 0, 0, 0);
            acc1 = __builtin_amdgcn_mfma_f32_16x16x32_bf16(pa, v1, acc1, 0, 0, 0);
        }
    }

    if (!is_cls) {
        float* Ob = O + ((long)bh * SP + qb * 64 + w * 16) * HD;
        #pragma unroll
        for (int r = 0; r < 4; r++) {
            float inv = 1.f / l_run[r];
            Ob[(hi * 4 + r) * HD + l15]      = acc0[r] * inv;
            Ob[(hi * 4 + r) * HD + 16 + l15] = acc1[r] * inv;
        }
    } else {
        #pragma unroll
        for (int r = 0; r < 4; r++) {
            int row = hi * 4 + r;
            if (l15 == 0) { Ms[w][row] = m_run[r]; Ls[w][row] = l_run[r]; }
            MAcc[w][row][l15]      = acc0[r];
            MAcc[w][row][16 + l15] = acc1[r];
        }
        __syncthreads();
        if (w == 0) {
            float* Ob = O + ((long)bh * SP + WN * 64) * HD;
            #pragma unroll
            for (int r = 0; r < 4; r++) {
                int row = hi * 4 + r;
                float M = fmaxf(fmaxf(Ms[0][row], Ms[1][row]),
                                fmaxf(Ms[2][row], Ms[3][row]));
                float L = 0.f, o0 = 0.f, o1 = 0.f;
                #pragma unroll
                for (int ww = 0; ww < 4; ww++) {
                    float sc = __expf(Ms[ww][row] - M);
                    L  += Ls[ww][row] * sc;
                    o0 += MAcc[ww][row][l15] * sc;
                    o1 += MAcc[ww][row][16 + l15] * sc;
                }
                float inv = 1.f / L;
                Ob[row * HD + l15]      = o0 * inv;
                Ob[row * HD + 16 + l15] = o1 * inv;
            }
        }
    }
}

// ---------------------------------------------------------------- gather + LEPE
__global__ __launch_bounds__(256) void assemble_u(
        const float* __restrict__ O, const float* __restrict__ Vsp,
        const float* __restrict__ lepe_w, const float* __restrict__ lepe_b,
        short* __restrict__ U) {
    int row = blockIdx.x;            // b*SS + tok
    int b = row / SS, tok = row % SS;
    int c = threadIdx.x;
    int head = c >> 5, d = c & 31;
    int s;
    float lepe = 0.f;
    if (tok < SIMG) {
        int h = tok / Wimg, w = tok % Wimg;
        s = (((h >> 3) * 7 + (w >> 3)) << 6) | ((h & 7) << 3) | (w & 7);
        float acc = lepe_b[c];
        #pragma unroll
        for (int dh = -1; dh <= 1; dh++) {
            int hh = h + dh;
            if (hh < 0 || hh >= Himg) continue;
            #pragma unroll
            for (int dw = -1; dw <= 1; dw++) {
                int ww = w + dw;
                if (ww < 0 || ww >= Wimg) continue;
                acc += Vsp[((long)(b * SIMG) + hh * Wimg + ww) * CC + c]
                     * lepe_w[((dh + 1) * 3 + (dw + 1)) * CC + c];
            }
        }
        lepe = acc;
    } else {
        s = tok;
    }
    float o = O[(((long)(b * NHd + head)) * SP + s) * HD + d];
    // U row index uses padded layout rows 0..6302 (b*SS+tok)
    U[(long)row * CC + c] = f2bf(o + lepe);
}

// ---------------------------------------------------------------- out GEMM (MFMA)
__global__ __launch_bounds__(256) void out_gemm_mfma(
        const short* __restrict__ U, const short* __restrict__ Wot,
        const float* __restrict__ bo, float* __restrict__ out) {
    int tid = threadIdx.x;
    int w = tid >> 6, l = tid & 63, l15 = l & 15, hi = l >> 4;
    int row0 = blockIdx.x * 64 + w * 16;
    int n0 = blockIdx.y * 64;
    f32x4 acc[4];
    #pragma unroll
    for (int t = 0; t < 4; t++) acc[t] = (f32x4){0.f, 0.f, 0.f, 0.f};
    const short* Ap = U + (long)(row0 + l15) * CC + hi * 8;
    const short* Bp = Wot + (long)(n0 + l15) * CC + hi * 8;
    #pragma unroll
    for (int k0 = 0; k0 < 256; k0 += 32) {
        bf16x8 af = *(const bf16x8*)(Ap + k0);
        #pragma unroll
        for (int t = 0; t < 4; t++) {
            bf16x8 bf = *(const bf16x8*)(Bp + t * 16 * CC + k0);
            acc[t] = __builtin_amdgcn_mfma_f32_16x16x32_bf16(af, bf, acc[t], 0, 0, 0);
        }
    }
    const int nrows = Bsz * SS;      // 6302
    #pragma unroll
    for (int r = 0; r < 4; r++) {
        int row = row0 + hi * 4 + r;
        if (row >= nrows) continue;
        int b = row / SS, tok = row % SS;
        long base;
        if (tok < SIMG) base = (long)(b * SIMG + tok) * CC;
        else base = (long)Bsz * SIMG * CC + (long)(b * NQtok + tok - SIMG) * CC;
        #pragma unroll
        for (int t = 0; t < 4; t++) {
            int n = n0 + t * 16 + l15;
            out[base + n] = acc[t][r] + bo[n];
        }
    }
}

// ---------------------------------------------------------------- launch
extern "C" void kernel_launch(void* const* d_in, const int* in_sizes, int n_in,
                              void* d_out, int out_size, void* d_ws, size_t ws_size,
                              hipStream_t stream) {
    const float* x      = (const float*)d_in[0];
    const float* cls    = (const float*)d_in[1];
    const unsigned char* mask_raw = (const unsigned char*)d_in[2];
    const float* Wqkv   = (const float*)d_in[3];
    const float* bqkv   = (const float*)d_in[4];
    const float* lepe_w = (const float*)d_in[5];
    const float* lepe_b = (const float*)d_in[6];
    const float* Wo     = (const float*)d_in[7];
    const float* bo     = (const float*)d_in[8];
    float* out = (float*)d_out;

    short* Qbf = (short*)d_ws;
    short* Kbf = Qbf + QSZ;
    short* Vtb = Kbf + QSZ;
    short* Abf = Vtb + QSZ;
    short* Wt  = Abf + ASZ;
    short* Wot = Wt + WTSZ;
    short* U   = Wot + WOTSZ;
    float* O   = (float*)(U + USZ2);
    float* Vsp = O + QSZ;
    unsigned char* mask8 = (unsigned char*)(Vsp + VSPSZ);

    prep_mask<<<1, 256, 0, stream>>>(mask_raw, mask8);
    cast_prep<<<928, 256, 0, stream>>>(x, cls, Wqkv, Wo, Abf, Wt, Wot);
    qkv_gemm_mfma<<<dim3(MROWS / 64, 12), 256, 0, stream>>>(Abf, Wt, bqkv, Qbf, Kbf, Vtb, Vsp);
    attn_mfma<<<Bsz * NHd * NWIN, 256, 0, stream>>>(Qbf, Kbf, Vtb, mask8, O);
    assemble_u<<<Bsz * SS, 256, 0, stream>>>(O, Vsp, lepe_w, lepe_b, U);
    out_gemm_mfma<<<dim3(MROWS / 64, 4), 256, 0, stream>>>(U, Wot, bo, out);
}